// Round 1
// baseline (790.896 us; speedup 1.0000x reference)
//
#include <hip/hip_runtime.h>
#include <stdint.h>

#define Bn 2
#define Nn 30000
#define En 120000
#define KIN 512
#define Hh 4
#define Dd 128
#define MROWS 60000            // B*N rows
#define MPAD  60032            // 469 * 128
#define LNEPS 1e-5f

typedef unsigned short u16;
typedef unsigned int   u32;
typedef __attribute__((ext_vector_type(8))) short short8;
typedef __attribute__((ext_vector_type(4))) float f32x4;

__device__ __forceinline__ u16 f2bf(float f) {
    u32 u = __builtin_bit_cast(u32, f);
    u32 r = u + 0x7FFFu + ((u >> 16) & 1u);
    return (u16)(r >> 16);
}
__device__ __forceinline__ float bf2f(u16 h) {
    u32 u = ((u32)h) << 16;
    return __builtin_bit_cast(float, u);
}
__device__ __forceinline__ u32 fkey(float f) {
    u32 u = __builtin_bit_cast(u32, f);
    return (u & 0x80000000u) ? ~u : (u | 0x80000000u);
}
__device__ __forceinline__ float funkey(u32 k) {
    u32 u = (k & 0x80000000u) ? (k & 0x7FFFFFFFu) : ~k;
    return __builtin_bit_cast(float, u);
}
__device__ __forceinline__ void ld16(void* lds, const void* g) {
    __builtin_amdgcn_global_load_lds((const __attribute__((address_space(1))) void*)g,
                                     (__attribute__((address_space(3))) void*)lds, 16, 0, 0);
}

// ---- kernel 0a: x fp32 -> bf16, zero-pad rows [60000, 60032) ----
__global__ void cvt_x(const float* __restrict__ x, u16* __restrict__ xb) {
    long i8 = (long)blockIdx.x * 256 + threadIdx.x;
    long base = i8 * 8;
    if (base >= (long)MPAD * KIN) return;
    short8 o = {};
    if (base < (long)MROWS * KIN) {
        const float4* px = (const float4*)(x + base);
        float4 v0 = px[0], v1 = px[1];
        o[0] = (short)f2bf(v0.x); o[1] = (short)f2bf(v0.y);
        o[2] = (short)f2bf(v0.z); o[3] = (short)f2bf(v0.w);
        o[4] = (short)f2bf(v1.x); o[5] = (short)f2bf(v1.y);
        o[6] = (short)f2bf(v1.z); o[7] = (short)f2bf(v1.w);
    }
    *(short8*)(xb + base) = o;
}

// ---- kernel 0b: W (H,512,128) fp32 -> B^T bf16 layout wbt[c][i], c=h*128+d ----
__global__ void cvt_w(const float* __restrict__ W, u16* __restrict__ wbt) {
    int idx = blockIdx.x * 256 + threadIdx.x;
    if (idx >= 512 * 512) return;
    int c = idx >> 9, i = idx & 511;
    int h = c >> 7, d = c & 127;
    wbt[idx] = f2bf(W[h * (KIN * Dd) + i * Dd + d]);
}

// ---- kernel 1: GEMM  t[row, c] = sum_k xb[row,k] * wbt[c,k]  (bf16 MFMA, m97 pattern) ----
__launch_bounds__(256)
__global__ void gemm(const u16* __restrict__ xb, const u16* __restrict__ wbt,
                     u16* __restrict__ t) {
    __shared__ __align__(16) u16 As[128 * 32];
    __shared__ __align__(16) u16 Bs[128 * 32];
    const int tid = threadIdx.x;
    const int m0 = blockIdx.y * 128, n0 = blockIdx.x * 128;
    const int w = tid >> 6, l = tid & 63;
    const int wr = (w >> 1) * 64, wc = (w & 1) * 64;
    const int lr = l & 15, lk = l >> 4;
    f32x4 acc[4][4] = {};

    for (int k0 = 0; k0 < KIN; k0 += 32) {
        // stage A(128x32) and B^T(128x32): 512 chunks of 16B each, 2 per thread
        #pragma unroll
        for (int inst = 0; inst < 2; inst++) {
            int q = inst * 256 + tid;
            const u16* ga = xb  + (long)(m0 + (q >> 2)) * KIN + k0 + (q & 3) * 8;
            const u16* gb = wbt + (long)(n0 + (q >> 2)) * KIN + k0 + (q & 3) * 8;
            ld16(&As[q * 8], ga);
            ld16(&Bs[q * 8], gb);
        }
        __syncthreads();
        short8 af[4], bfr[4];
        #pragma unroll
        for (int mi = 0; mi < 4; mi++)
            af[mi] = *(const short8*)&As[(wr + mi * 16 + lr) * 32 + lk * 8];
        #pragma unroll
        for (int nj = 0; nj < 4; nj++)
            bfr[nj] = *(const short8*)&Bs[(wc + nj * 16 + lr) * 32 + lk * 8];
        #pragma unroll
        for (int mi = 0; mi < 4; mi++)
            #pragma unroll
            for (int nj = 0; nj < 4; nj++)
                acc[mi][nj] = __builtin_amdgcn_mfma_f32_16x16x32_bf16(
                    af[mi], bfr[nj], acc[mi][nj], 0, 0, 0);
        __syncthreads();
    }
    // epilogue: C/D map col=lane&15, row=(lane>>4)*4+reg  [m89/m91 verified]
    #pragma unroll
    for (int mi = 0; mi < 4; mi++)
        #pragma unroll
        for (int r = 0; r < 4; r++) {
            int row = m0 + wr + mi * 16 + lk * 4 + r;
            u16* tp = t + (long)row * 512 + n0 + wc + lr;
            #pragma unroll
            for (int nj = 0; nj < 4; nj++)
                tp[nj * 16] = f2bf(acc[mi][nj][r]);
        }
}

// ---- kernel 2: per-node score halves. wave per row, 16 lanes per head ----
__global__ void s1s2_kernel(const u16* __restrict__ t, const float* __restrict__ a,
                            float* __restrict__ s1, float* __restrict__ s2) {
    int row = blockIdx.x * 4 + (threadIdx.x >> 6);
    if (row >= MROWS) return;
    int l = threadIdx.x & 63;
    int h = l >> 4, dl = (l & 15) * 8;
    short8 tv = *(const short8*)(t + (long)row * 512 + h * 128 + dl);
    const float* a1 = a + h * 256 + dl;
    const float* a2 = a1 + 128;
    float p1 = 0.f, p2 = 0.f;
    #pragma unroll
    for (int j = 0; j < 8; j++) {
        float tf = bf2f((u16)tv[j]);
        p1 += tf * a1[j];
        p2 += tf * a2[j];
    }
    #pragma unroll
    for (int off = 1; off < 16; off <<= 1) {
        p1 += __shfl_xor(p1, off, 64);
        p2 += __shfl_xor(p2, off, 64);
    }
    if ((l & 15) == 0) {
        s1[(long)row * 4 + h] = p1;
        s2[(long)row * 4 + h] = p2;
    }
}

// ---- kernel 3: edge scores + leaky relu + global max per (b,h) ----
__global__ void score_kernel(const int* __restrict__ ei, const float* __restrict__ s1,
                             const float* __restrict__ s2, float* __restrict__ sc,
                             u32* __restrict__ mkey) {
    int e = blockIdx.x * 256 + threadIdx.x;
    int b = blockIdx.y;
    float v[4] = {-1e30f, -1e30f, -1e30f, -1e30f};
    if (e < En) {
        int src = ei[e], dst = ei[En + e];
        const float* p1 = s1 + ((long)b * Nn + src) * 4;
        const float* p2 = s2 + ((long)b * Nn + dst) * 4;
        #pragma unroll
        for (int h = 0; h < 4; h++) {
            float s = p1[h] + p2[h];
            v[h] = s > 0.f ? s : 0.2f * s;
        }
        float4 o = make_float4(v[0], v[1], v[2], v[3]);
        *(float4*)(sc + ((long)b * En + e) * 4) = o;
    }
    #pragma unroll
    for (int off = 1; off < 64; off <<= 1)
        #pragma unroll
        for (int h = 0; h < 4; h++)
            v[h] = fmaxf(v[h], __shfl_xor(v[h], off, 64));
    if ((threadIdx.x & 63) == 0)
        #pragma unroll
        for (int h = 0; h < 4; h++)
            atomicMax(&mkey[b * 4 + h], fkey(v[h]));
}

// ---- kernel 4: p = exp(sc - max), Z partial sums ----
__global__ void exp_kernel(float* __restrict__ sc, const u32* __restrict__ mkey,
                           float* __restrict__ Z) {
    int e = blockIdx.x * 256 + threadIdx.x;
    int b = blockIdx.y;
    float s[4] = {0.f, 0.f, 0.f, 0.f};
    if (e < En) {
        float4 v = *(float4*)(sc + ((long)b * En + e) * 4);
        float m0 = funkey(mkey[b * 4 + 0]);
        float m1 = funkey(mkey[b * 4 + 1]);
        float m2 = funkey(mkey[b * 4 + 2]);
        float m3 = funkey(mkey[b * 4 + 3]);
        v.x = __expf(v.x - m0); v.y = __expf(v.y - m1);
        v.z = __expf(v.z - m2); v.w = __expf(v.w - m3);
        *(float4*)(sc + ((long)b * En + e) * 4) = v;
        s[0] = v.x; s[1] = v.y; s[2] = v.z; s[3] = v.w;
    }
    #pragma unroll
    for (int off = 1; off < 64; off <<= 1)
        #pragma unroll
        for (int h = 0; h < 4; h++)
            s[h] += __shfl_xor(s[h], off, 64);
    if ((threadIdx.x & 63) == 0)
        #pragma unroll
        for (int h = 0; h < 4; h++)
            atomicAdd(&Z[b * 4 + h], s[h]);
}

// ---- kernel 5a: degree histogram ----
__global__ void hist_kernel(const int* __restrict__ ei, int* __restrict__ deg) {
    int e = blockIdx.x * 256 + threadIdx.x;
    if (e < En) atomicAdd(&deg[ei[En + e]], 1);
}

// ---- kernel 5b: exclusive scan (single block, 1024 threads) ----
__global__ void scan_kernel(const int* __restrict__ deg, int* __restrict__ offs,
                            int* __restrict__ cursor) {
    __shared__ int part[1024];
    int tid = threadIdx.x;
    const int CH = (Nn + 1023) / 1024;  // 30
    int start = tid * CH;
    int s = 0;
    for (int i = 0; i < CH; i++) {
        int n = start + i;
        if (n < Nn) s += deg[n];
    }
    part[tid] = s;
    __syncthreads();
    for (int off = 1; off < 1024; off <<= 1) {
        int x = (tid >= off) ? part[tid - off] : 0;
        __syncthreads();
        part[tid] += x;
        __syncthreads();
    }
    int run = part[tid] - s;  // exclusive prefix at chunk start
    for (int i = 0; i < CH; i++) {
        int n = start + i;
        if (n < Nn) {
            offs[n] = run;
            cursor[n] = run;
            run += deg[n];
        }
    }
    if (tid == 1023) offs[Nn] = part[1023];
}

// ---- kernel 5c: scatter edge ids grouped by dst ----
__global__ void scatter_kernel(const int* __restrict__ ei, int* __restrict__ cursor,
                               int* __restrict__ elist) {
    int e = blockIdx.x * 256 + threadIdx.x;
    if (e < En) {
        int d = ei[En + e];
        int pos = atomicAdd(&cursor[d], 1);
        elist[pos] = e;
    }
}

// ---- kernel 6: aggregation (no atomics) + fused LayerNorm ----
__launch_bounds__(128)
__global__ void agg_kernel(const u16* __restrict__ t, const int* __restrict__ ei,
                           const float* __restrict__ p, const float* __restrict__ Z,
                           const int* __restrict__ offs, const int* __restrict__ elist,
                           const float* __restrict__ gamma, const float* __restrict__ beta,
                           float* __restrict__ out) {
    int n = blockIdx.x, b = blockIdx.y;
    int tid = threadIdx.x;          // owns cols 4*tid .. 4*tid+3, head = tid>>5
    float invz = 1.0f / Z[b * 4 + (tid >> 5)];
    int j0 = offs[n], j1 = offs[n + 1];
    const float* pb = p + (long)b * En * 4;
    const u16* tb = t + (long)b * Nn * 512;
    float a0 = 0.f, a1 = 0.f, a2 = 0.f, a3 = 0.f;
    for (int j = j0; j < j1; j++) {
        int e = elist[j];
        int src = ei[e];
        float w = pb[(long)e * 4 + (tid >> 5)] * invz;
        uint2 raw = *(const uint2*)(tb + (long)src * 512 + tid * 4);
        a0 += w * __builtin_bit_cast(float, raw.x << 16);
        a1 += w * __builtin_bit_cast(float, raw.x & 0xFFFF0000u);
        a2 += w * __builtin_bit_cast(float, raw.y << 16);
        a3 += w * __builtin_bit_cast(float, raw.y & 0xFFFF0000u);
    }
    // fused LayerNorm over the 512 cols held by this block
    float s  = a0 + a1 + a2 + a3;
    float ss = a0 * a0 + a1 * a1 + a2 * a2 + a3 * a3;
    #pragma unroll
    for (int off = 1; off < 64; off <<= 1) {
        s  += __shfl_xor(s, off, 64);
        ss += __shfl_xor(ss, off, 64);
    }
    __shared__ float red[4];
    if ((tid & 63) == 0) {
        red[(tid >> 6) * 2]     = s;
        red[(tid >> 6) * 2 + 1] = ss;
    }
    __syncthreads();
    s  = red[0] + red[2];
    ss = red[1] + red[3];
    float mean = s * (1.0f / 512.0f);
    float var = ss * (1.0f / 512.0f) - mean * mean;
    var = var < 0.f ? 0.f : var;
    float scale = rsqrtf(var + LNEPS);
    int c = tid * 4;
    float4 o;
    o.x = (a0 - mean) * scale * gamma[c + 0] + beta[c + 0];
    o.y = (a1 - mean) * scale * gamma[c + 1] + beta[c + 1];
    o.z = (a2 - mean) * scale * gamma[c + 2] + beta[c + 2];
    o.w = (a3 - mean) * scale * gamma[c + 3] + beta[c + 3];
    *(float4*)(out + ((long)b * Nn + n) * 512 + c) = o;
}

extern "C" void kernel_launch(void* const* d_in, const int* in_sizes, int n_in,
                              void* d_out, int out_size, void* d_ws, size_t ws_size,
                              hipStream_t stream) {
    const float* x     = (const float*)d_in[0];
    const int*   ei    = (const int*)d_in[1];   // (2,E) int32 (JAX demotes int64)
    const float* W     = (const float*)d_in[2];
    const float* a     = (const float*)d_in[3];
    const float* gamma = (const float*)d_in[4];
    const float* beta  = (const float*)d_in[5];
    float* out = (float*)d_out;

    char* ws = (char*)d_ws;
    size_t off = 0;
    auto alloc = [&](size_t bytes) -> void* {
        void* ptr = ws + off;
        off = (off + bytes + 255) & ~(size_t)255;
        return ptr;
    };
    u16*   xb     = (u16*)alloc((size_t)MPAD * KIN * 2);       // 61.5 MB
    u16*   wbt    = (u16*)alloc((size_t)512 * 512 * 2);        // 0.5 MB
    u16*   t      = (u16*)alloc((size_t)MPAD * 512 * 2);       // 61.5 MB
    float* s1     = (float*)alloc((size_t)MROWS * 4 * 4);
    float* s2     = (float*)alloc((size_t)MROWS * 4 * 4);
    float* sc     = (float*)alloc((size_t)Bn * En * 4 * 4);    // scores then p
    char*  mz     = (char*)alloc(64 + (size_t)Nn * 4);         // mkey|Z|deg, memset 0
    u32*   mkey   = (u32*)mz;
    float* Z      = (float*)(mz + 32);
    int*   deg    = (int*)(mz + 64);
    int*   offs   = (int*)alloc((size_t)(Nn + 1) * 4);
    int*   cursor = (int*)alloc((size_t)Nn * 4);
    int*   elist  = (int*)alloc((size_t)En * 4);

    hipMemsetAsync(mz, 0, 64 + (size_t)Nn * 4, stream);

    cvt_x<<<(int)(((long)MPAD * KIN / 8 + 255) / 256), 256, 0, stream>>>(x, xb);
    cvt_w<<<(512 * 512) / 256, 256, 0, stream>>>(W, wbt);
    gemm<<<dim3(4, MPAD / 128), 256, 0, stream>>>(xb, wbt, t);
    s1s2_kernel<<<MROWS / 4, 256, 0, stream>>>(t, a, s1, s2);
    score_kernel<<<dim3((En + 255) / 256, Bn), 256, 0, stream>>>(ei, s1, s2, sc, mkey);
    exp_kernel<<<dim3((En + 255) / 256, Bn), 256, 0, stream>>>(sc, mkey, Z);
    hist_kernel<<<(En + 255) / 256, 256, 0, stream>>>(ei, deg);
    scan_kernel<<<1, 1024, 0, stream>>>(deg, offs, cursor);
    scatter_kernel<<<(En + 255) / 256, 256, 0, stream>>>(ei, cursor, elist);
    agg_kernel<<<dim3(Nn, Bn), 128, 0, stream>>>(t, ei, sc, Z, offs, elist, gamma, beta, out);
}

// Round 2
// 436.616 us; speedup vs baseline: 1.8114x; 1.8114x over previous
//
#include <hip/hip_runtime.h>
#include <stdint.h>

#define Bn 2
#define Nn 30000
#define En 120000
#define KIN 512
#define Hh 4
#define Dd 128
#define MROWS 60000            // B*N rows
#define MPAD  60032            // 469 * 128
#define LNEPS 1e-5f
#define EBLK 469               // ceil(En/256)

typedef unsigned short u16;
typedef unsigned int   u32;
typedef __attribute__((ext_vector_type(8))) short short8;
typedef __attribute__((ext_vector_type(4))) float f32x4;

__device__ __forceinline__ u16 f2bf(float f) {
    u32 u = __builtin_bit_cast(u32, f);
    u32 r = u + 0x7FFFu + ((u >> 16) & 1u);
    return (u16)(r >> 16);
}
__device__ __forceinline__ float bf2f(u16 h) {
    u32 u = ((u32)h) << 16;
    return __builtin_bit_cast(float, u);
}
__device__ __forceinline__ void ld16(void* lds, const void* g) {
    __builtin_amdgcn_global_load_lds((const __attribute__((address_space(1))) void*)g,
                                     (__attribute__((address_space(3))) void*)lds, 16, 0, 0);
}

// ---- kernel 0a: x fp32 -> bf16, zero-pad rows [60000, 60032) ----
__global__ void cvt_x(const float* __restrict__ x, u16* __restrict__ xb) {
    long i8 = (long)blockIdx.x * 256 + threadIdx.x;
    long base = i8 * 8;
    if (base >= (long)MPAD * KIN) return;
    short8 o = {};
    if (base < (long)MROWS * KIN) {
        const float4* px = (const float4*)(x + base);
        float4 v0 = px[0], v1 = px[1];
        o[0] = (short)f2bf(v0.x); o[1] = (short)f2bf(v0.y);
        o[2] = (short)f2bf(v0.z); o[3] = (short)f2bf(v0.w);
        o[4] = (short)f2bf(v1.x); o[5] = (short)f2bf(v1.y);
        o[6] = (short)f2bf(v1.z); o[7] = (short)f2bf(v1.w);
    }
    *(short8*)(xb + base) = o;
}

// ---- kernel 0b: W (H,512,128) fp32 -> B^T bf16 layout wbt[c][i], c=h*128+d ----
__global__ void cvt_w(const float* __restrict__ W, u16* __restrict__ wbt) {
    int idx = blockIdx.x * 256 + threadIdx.x;
    if (idx >= 512 * 512) return;
    int c = idx >> 9, i = idx & 511;
    int h = c >> 7, d = c & 127;
    wbt[idx] = f2bf(W[h * (KIN * Dd) + i * Dd + d]);
}

// ---- kernel 1: GEMM  t[row, c] = sum_k xb[row,k] * wbt[c,k]  (bf16 MFMA, m97 pattern) ----
__launch_bounds__(256)
__global__ void gemm(const u16* __restrict__ xb, const u16* __restrict__ wbt,
                     u16* __restrict__ t) {
    __shared__ __align__(16) u16 As[128 * 32];
    __shared__ __align__(16) u16 Bs[128 * 32];
    const int tid = threadIdx.x;
    const int m0 = blockIdx.y * 128, n0 = blockIdx.x * 128;
    const int w = tid >> 6, l = tid & 63;
    const int wr = (w >> 1) * 64, wc = (w & 1) * 64;
    const int lr = l & 15, lk = l >> 4;
    f32x4 acc[4][4] = {};

    for (int k0 = 0; k0 < KIN; k0 += 32) {
        #pragma unroll
        for (int inst = 0; inst < 2; inst++) {
            int q = inst * 256 + tid;
            const u16* ga = xb  + (long)(m0 + (q >> 2)) * KIN + k0 + (q & 3) * 8;
            const u16* gb = wbt + (long)(n0 + (q >> 2)) * KIN + k0 + (q & 3) * 8;
            ld16(&As[q * 8], ga);
            ld16(&Bs[q * 8], gb);
        }
        __syncthreads();
        short8 af[4], bfr[4];
        #pragma unroll
        for (int mi = 0; mi < 4; mi++)
            af[mi] = *(const short8*)&As[(wr + mi * 16 + lr) * 32 + lk * 8];
        #pragma unroll
        for (int nj = 0; nj < 4; nj++)
            bfr[nj] = *(const short8*)&Bs[(wc + nj * 16 + lr) * 32 + lk * 8];
        #pragma unroll
        for (int mi = 0; mi < 4; mi++)
            #pragma unroll
            for (int nj = 0; nj < 4; nj++)
                acc[mi][nj] = __builtin_amdgcn_mfma_f32_16x16x32_bf16(
                    af[mi], bfr[nj], acc[mi][nj], 0, 0, 0);
        __syncthreads();
    }
    #pragma unroll
    for (int mi = 0; mi < 4; mi++)
        #pragma unroll
        for (int r = 0; r < 4; r++) {
            int row = m0 + wr + mi * 16 + lk * 4 + r;
            u16* tp = t + (long)row * 512 + n0 + wc + lr;
            #pragma unroll
            for (int nj = 0; nj < 4; nj++)
                tp[nj * 16] = f2bf(acc[mi][nj][r]);
        }
}

// ---- kernel 2: per-node score halves. wave per row, 16 lanes per head ----
__global__ void s1s2_kernel(const u16* __restrict__ t, const float* __restrict__ a,
                            float* __restrict__ s1, float* __restrict__ s2) {
    int row = blockIdx.x * 4 + (threadIdx.x >> 6);
    if (row >= MROWS) return;
    int l = threadIdx.x & 63;
    int h = l >> 4, dl = (l & 15) * 8;
    short8 tv = *(const short8*)(t + (long)row * 512 + h * 128 + dl);
    const float* a1 = a + h * 256 + dl;
    const float* a2 = a1 + 128;
    float p1 = 0.f, p2 = 0.f;
    #pragma unroll
    for (int j = 0; j < 8; j++) {
        float tf = bf2f((u16)tv[j]);
        p1 += tf * a1[j];
        p2 += tf * a2[j];
    }
    #pragma unroll
    for (int off = 1; off < 16; off <<= 1) {
        p1 += __shfl_xor(p1, off, 64);
        p2 += __shfl_xor(p2, off, 64);
    }
    if ((l & 15) == 0) {
        s1[(long)row * 4 + h] = p1;
        s2[(long)row * 4 + h] = p2;
    }
}

// ---- kernel 2b: per-(b,h) node-wise maxes of s1,s2 -> block partials ----
__global__ void nodemax_kernel(const float* __restrict__ s1, const float* __restrict__ s2,
                               float* __restrict__ pmax) {
    int b = blockIdx.y, tid = threadIdx.x;
    float m1[4] = {-1e30f, -1e30f, -1e30f, -1e30f};
    float m2[4] = {-1e30f, -1e30f, -1e30f, -1e30f};
    for (int n = blockIdx.x * 256 + tid; n < Nn; n += 32 * 256) {
        float4 v1 = *(const float4*)(s1 + ((long)b * Nn + n) * 4);
        float4 v2 = *(const float4*)(s2 + ((long)b * Nn + n) * 4);
        m1[0] = fmaxf(m1[0], v1.x); m1[1] = fmaxf(m1[1], v1.y);
        m1[2] = fmaxf(m1[2], v1.z); m1[3] = fmaxf(m1[3], v1.w);
        m2[0] = fmaxf(m2[0], v2.x); m2[1] = fmaxf(m2[1], v2.y);
        m2[2] = fmaxf(m2[2], v2.z); m2[3] = fmaxf(m2[3], v2.w);
    }
    #pragma unroll
    for (int off = 1; off < 64; off <<= 1)
        #pragma unroll
        for (int h = 0; h < 4; h++) {
            m1[h] = fmaxf(m1[h], __shfl_xor(m1[h], off, 64));
            m2[h] = fmaxf(m2[h], __shfl_xor(m2[h], off, 64));
        }
    __shared__ float red[4][8];
    if ((tid & 63) == 0)
        #pragma unroll
        for (int h = 0; h < 4; h++) {
            red[tid >> 6][h] = m1[h];
            red[tid >> 6][h + 4] = m2[h];
        }
    __syncthreads();
    if (tid < 8) {
        float m = fmaxf(fmaxf(red[0][tid], red[1][tid]), fmaxf(red[2][tid], red[3][tid]));
        // layout: pmax[((b*32 + blk)*2 + half)*4 + h]
        pmax[((b * 32 + blockIdx.x) * 8) + tid] = m;
    }
}

// ---- kernel 2c: reduce partials -> M[b*4+h] = leaky(m1+m2) (upper bound on max score) ----
__global__ void mreduce_kernel(const float* __restrict__ pmax, float* __restrict__ M) {
    int tid = threadIdx.x;   // 8 active lanes: b*4+h
    if (tid < 8) {
        int b = tid >> 2, h = tid & 3;
        float m1 = -1e30f, m2 = -1e30f;
        for (int blk = 0; blk < 32; blk++) {
            m1 = fmaxf(m1, pmax[(b * 32 + blk) * 8 + h]);
            m2 = fmaxf(m2, pmax[(b * 32 + blk) * 8 + 4 + h]);
        }
        float s = m1 + m2;
        M[tid] = s > 0.f ? s : 0.2f * s;
    }
}

// ---- kernel 3: fused edge pass: score + leaky + exp(.-M) + Z block partials ----
__global__ void edge_kernel(const int* __restrict__ ei, const float* __restrict__ s1,
                            const float* __restrict__ s2, const float* __restrict__ M,
                            float* __restrict__ p, float* __restrict__ Zpart) {
    int e = blockIdx.x * 256 + threadIdx.x;
    int b = blockIdx.y;
    float v[4] = {0.f, 0.f, 0.f, 0.f};
    float m0 = M[b * 4 + 0], m1 = M[b * 4 + 1], m2 = M[b * 4 + 2], m3 = M[b * 4 + 3];
    if (e < En) {
        int src = ei[e], dst = ei[En + e];
        float4 v1 = *(const float4*)(s1 + ((long)b * Nn + src) * 4);
        float4 v2 = *(const float4*)(s2 + ((long)b * Nn + dst) * 4);
        float s;
        s = v1.x + v2.x; s = s > 0.f ? s : 0.2f * s; v[0] = __expf(s - m0);
        s = v1.y + v2.y; s = s > 0.f ? s : 0.2f * s; v[1] = __expf(s - m1);
        s = v1.z + v2.z; s = s > 0.f ? s : 0.2f * s; v[2] = __expf(s - m2);
        s = v1.w + v2.w; s = s > 0.f ? s : 0.2f * s; v[3] = __expf(s - m3);
        float4 o = make_float4(v[0], v[1], v[2], v[3]);
        *(float4*)(p + ((long)b * En + e) * 4) = o;
    }
    #pragma unroll
    for (int off = 1; off < 64; off <<= 1)
        #pragma unroll
        for (int h = 0; h < 4; h++)
            v[h] += __shfl_xor(v[h], off, 64);
    __shared__ float red[4][4];
    int tid = threadIdx.x;
    if ((tid & 63) == 0)
        #pragma unroll
        for (int h = 0; h < 4; h++)
            red[tid >> 6][h] = v[h];
    __syncthreads();
    if (tid < 4) {
        float z = red[0][tid] + red[1][tid] + red[2][tid] + red[3][tid];
        Zpart[((long)b * EBLK + blockIdx.x) * 4 + tid] = z;
    }
}

// ---- kernel 4: reduce Z partials -> invZ[b*4+h] ----
__global__ void zreduce_kernel(const float* __restrict__ Zpart, float* __restrict__ invZ) {
    int tid = threadIdx.x;          // 512 threads: group g=tid>>6 is (b*4+h), 64 lanes each
    int g = tid >> 6, l = tid & 63;
    int b = g >> 2, h = g & 3;
    float s = 0.f;
    for (int i = l; i < EBLK; i += 64)
        s += Zpart[((long)b * EBLK + i) * 4 + h];
    #pragma unroll
    for (int off = 1; off < 64; off <<= 1)
        s += __shfl_xor(s, off, 64);
    if (l == 0) invZ[g] = 1.0f / s;
}

// ---- kernel 5a: degree histogram ----
__global__ void hist_kernel(const int* __restrict__ ei, int* __restrict__ deg) {
    int e = blockIdx.x * 256 + threadIdx.x;
    if (e < En) atomicAdd(&deg[ei[En + e]], 1);
}

// ---- kernel 5b: exclusive scan (single block, 1024 threads) ----
__global__ void scan_kernel(const int* __restrict__ deg, int* __restrict__ offs,
                            int* __restrict__ cursor) {
    __shared__ int part[1024];
    int tid = threadIdx.x;
    const int CH = (Nn + 1023) / 1024;  // 30
    int start = tid * CH;
    int s = 0;
    for (int i = 0; i < CH; i++) {
        int n = start + i;
        if (n < Nn) s += deg[n];
    }
    part[tid] = s;
    __syncthreads();
    for (int off = 1; off < 1024; off <<= 1) {
        int x = (tid >= off) ? part[tid - off] : 0;
        __syncthreads();
        part[tid] += x;
        __syncthreads();
    }
    int run = part[tid] - s;
    for (int i = 0; i < CH; i++) {
        int n = start + i;
        if (n < Nn) {
            offs[n] = run;
            cursor[n] = run;
            run += deg[n];
        }
    }
    if (tid == 1023) offs[Nn] = part[1023];
}

// ---- kernel 5c: scatter edge ids grouped by dst ----
__global__ void scatter_kernel(const int* __restrict__ ei, int* __restrict__ cursor,
                               int* __restrict__ elist) {
    int e = blockIdx.x * 256 + threadIdx.x;
    if (e < En) {
        int d = ei[En + e];
        int pos = atomicAdd(&cursor[d], 1);
        elist[pos] = e;
    }
}

// ---- kernel 6: aggregation (no atomics) + fused LayerNorm ----
__launch_bounds__(128)
__global__ void agg_kernel(const u16* __restrict__ t, const int* __restrict__ ei,
                           const float* __restrict__ p, const float* __restrict__ invZ,
                           const int* __restrict__ offs, const int* __restrict__ elist,
                           const float* __restrict__ gamma, const float* __restrict__ beta,
                           float* __restrict__ out) {
    int n = blockIdx.x, b = blockIdx.y;
    int tid = threadIdx.x;          // owns cols 4*tid .. 4*tid+3, head = tid>>5
    float invz = invZ[b * 4 + (tid >> 5)];
    int j0 = offs[n], j1 = offs[n + 1];
    const float* pb = p + (long)b * En * 4;
    const u16* tb = t + (long)b * Nn * 512;
    float a0 = 0.f, a1 = 0.f, a2 = 0.f, a3 = 0.f;
    for (int j = j0; j < j1; j++) {
        int e = elist[j];
        int src = ei[e];
        float w = pb[(long)e * 4 + (tid >> 5)] * invz;
        uint2 raw = *(const uint2*)(tb + (long)src * 512 + tid * 4);
        a0 += w * __builtin_bit_cast(float, raw.x << 16);
        a1 += w * __builtin_bit_cast(float, raw.x & 0xFFFF0000u);
        a2 += w * __builtin_bit_cast(float, raw.y << 16);
        a3 += w * __builtin_bit_cast(float, raw.y & 0xFFFF0000u);
    }
    float s  = a0 + a1 + a2 + a3;
    float ss = a0 * a0 + a1 * a1 + a2 * a2 + a3 * a3;
    #pragma unroll
    for (int off = 1; off < 64; off <<= 1) {
        s  += __shfl_xor(s, off, 64);
        ss += __shfl_xor(ss, off, 64);
    }
    __shared__ float red[4];
    if ((tid & 63) == 0) {
        red[(tid >> 6) * 2]     = s;
        red[(tid >> 6) * 2 + 1] = ss;
    }
    __syncthreads();
    s  = red[0] + red[2];
    ss = red[1] + red[3];
    float mean = s * (1.0f / 512.0f);
    float var = ss * (1.0f / 512.0f) - mean * mean;
    var = var < 0.f ? 0.f : var;
    float scale = rsqrtf(var + LNEPS);
    int c = tid * 4;
    float4 o;
    o.x = (a0 - mean) * scale * gamma[c + 0] + beta[c + 0];
    o.y = (a1 - mean) * scale * gamma[c + 1] + beta[c + 1];
    o.z = (a2 - mean) * scale * gamma[c + 2] + beta[c + 2];
    o.w = (a3 - mean) * scale * gamma[c + 3] + beta[c + 3];
    *(float4*)(out + ((long)b * Nn + n) * 512 + c) = o;
}

extern "C" void kernel_launch(void* const* d_in, const int* in_sizes, int n_in,
                              void* d_out, int out_size, void* d_ws, size_t ws_size,
                              hipStream_t stream) {
    const float* x     = (const float*)d_in[0];
    const int*   ei    = (const int*)d_in[1];   // (2,E) int32
    const float* W     = (const float*)d_in[2];
    const float* a     = (const float*)d_in[3];
    const float* gamma = (const float*)d_in[4];
    const float* beta  = (const float*)d_in[5];
    float* out = (float*)d_out;

    char* ws = (char*)d_ws;
    size_t off = 0;
    auto alloc = [&](size_t bytes) -> void* {
        void* ptr = ws + off;
        off = (off + bytes + 255) & ~(size_t)255;
        return ptr;
    };
    u16*   xb     = (u16*)alloc((size_t)MPAD * KIN * 2);       // 61.5 MB
    u16*   wbt    = (u16*)alloc((size_t)512 * 512 * 2);        // 0.5 MB
    u16*   t      = (u16*)alloc((size_t)MPAD * 512 * 2);       // 61.5 MB
    float* s1     = (float*)alloc((size_t)MROWS * 4 * 4);
    float* s2     = (float*)alloc((size_t)MROWS * 4 * 4);
    float* p      = (float*)alloc((size_t)Bn * En * 4 * 4);    // softmax numerators
    float* pmax   = (float*)alloc((size_t)Bn * 32 * 8 * 4);    // nodemax partials
    float* M      = (float*)alloc(8 * 4);
    float* Zpart  = (float*)alloc((size_t)Bn * EBLK * 4 * 4);
    float* invZ   = (float*)alloc(8 * 4);
    int*   deg    = (int*)alloc((size_t)Nn * 4);
    int*   offs   = (int*)alloc((size_t)(Nn + 1) * 4);
    int*   cursor = (int*)alloc((size_t)Nn * 4);
    int*   elist  = (int*)alloc((size_t)En * 4);

    hipMemsetAsync(deg, 0, (size_t)Nn * 4, stream);

    cvt_x<<<(int)(((long)MPAD * KIN / 8 + 255) / 256), 256, 0, stream>>>(x, xb);
    cvt_w<<<(512 * 512) / 256, 256, 0, stream>>>(W, wbt);
    gemm<<<dim3(4, MPAD / 128), 256, 0, stream>>>(xb, wbt, t);
    s1s2_kernel<<<MROWS / 4, 256, 0, stream>>>(t, a, s1, s2);
    nodemax_kernel<<<dim3(32, Bn), 256, 0, stream>>>(s1, s2, pmax);
    mreduce_kernel<<<1, 64, 0, stream>>>(pmax, M);
    edge_kernel<<<dim3(EBLK, Bn), 256, 0, stream>>>(ei, s1, s2, M, p, Zpart);
    zreduce_kernel<<<1, 512, 0, stream>>>(Zpart, invZ);
    hist_kernel<<<(En + 255) / 256, 256, 0, stream>>>(ei, deg);
    scan_kernel<<<1, 1024, 0, stream>>>(deg, offs, cursor);
    scatter_kernel<<<(En + 255) / 256, 256, 0, stream>>>(ei, cursor, elist);
    agg_kernel<<<dim3(Nn, Bn), 128, 0, stream>>>(t, ei, p, invZ, offs, elist, gamma, beta, out);
}

// Round 3
// 429.431 us; speedup vs baseline: 1.8417x; 1.0167x over previous
//
#include <hip/hip_runtime.h>
#include <stdint.h>

#define Bn 2
#define Nn 30000
#define En 120000
#define KIN 512
#define Hh 4
#define Dd 128
#define MROWS 60000            // B*N rows
#define MPAD  60032            // 469 * 128
#define LNEPS 1e-5f
#define EBLK 469               // ceil(En/256)

typedef unsigned short u16;
typedef unsigned int   u32;
typedef __attribute__((ext_vector_type(8))) short short8;
typedef __attribute__((ext_vector_type(4))) float f32x4;

__device__ __forceinline__ u16 f2bf(float f) {
    u32 u = __builtin_bit_cast(u32, f);
    u32 r = u + 0x7FFFu + ((u >> 16) & 1u);
    return (u16)(r >> 16);
}
__device__ __forceinline__ float bflo(u32 u) {
    return __builtin_bit_cast(float, u << 16);
}
__device__ __forceinline__ float bfhi(u32 u) {
    return __builtin_bit_cast(float, u & 0xFFFF0000u);
}
__device__ __forceinline__ void ld16(void* lds, const void* g) {
    __builtin_amdgcn_global_load_lds((const __attribute__((address_space(1))) void*)g,
                                     (__attribute__((address_space(3))) void*)lds, 16, 0, 0);
}

// ---- kernel 0a: x fp32 -> bf16, zero-pad rows [60000, 60032) ----
__global__ void cvt_x(const float* __restrict__ x, u16* __restrict__ xb) {
    long i8 = (long)blockIdx.x * 256 + threadIdx.x;
    long base = i8 * 8;
    if (base >= (long)MPAD * KIN) return;
    short8 o = {};
    if (base < (long)MROWS * KIN) {
        const float4* px = (const float4*)(x + base);
        float4 v0 = px[0], v1 = px[1];
        o[0] = (short)f2bf(v0.x); o[1] = (short)f2bf(v0.y);
        o[2] = (short)f2bf(v0.z); o[3] = (short)f2bf(v0.w);
        o[4] = (short)f2bf(v1.x); o[5] = (short)f2bf(v1.y);
        o[6] = (short)f2bf(v1.z); o[7] = (short)f2bf(v1.w);
    }
    *(short8*)(xb + base) = o;
}

// ---- kernel 0b: W (H,512,128) fp32 -> B^T bf16 layout wbt[c][i], c=h*128+d ----
__global__ void cvt_w(const float* __restrict__ W, u16* __restrict__ wbt) {
    int idx = blockIdx.x * 256 + threadIdx.x;
    if (idx >= 512 * 512) return;
    int c = idx >> 9, i = idx & 511;
    int h = c >> 7, d = c & 127;
    wbt[idx] = f2bf(W[h * (KIN * Dd) + i * Dd + d]);
}

// ---- kernel 1: GEMM t = xb * wbt^T (bf16 MFMA, m97 pattern) + fused s1/s2 epilogue ----
// Each block covers one head's full 128 cols (n-block == head), so s1/s2 for its
// 128 rows reduce entirely within the block from fp32 accumulators.
__launch_bounds__(256)
__global__ void gemm(const u16* __restrict__ xb, const u16* __restrict__ wbt,
                     const float* __restrict__ ag, u16* __restrict__ t,
                     float* __restrict__ s1g, float* __restrict__ s2g) {
    __shared__ __align__(16) u16 As[128 * 32];
    __shared__ __align__(16) u16 Bs[128 * 32];
    __shared__ float sred[2][2][128];   // [s1/s2][col-half][row]
    const int tid = threadIdx.x;
    const int m0 = blockIdx.y * 128, n0 = blockIdx.x * 128;
    const int w = tid >> 6, l = tid & 63;
    const int wr = (w >> 1) * 64, wc = (w & 1) * 64;
    const int lr = l & 15, lk = l >> 4;
    f32x4 acc[4][4] = {};

    for (int k0 = 0; k0 < KIN; k0 += 32) {
        #pragma unroll
        for (int inst = 0; inst < 2; inst++) {
            int q = inst * 256 + tid;
            const u16* gap = xb  + (long)(m0 + (q >> 2)) * KIN + k0 + (q & 3) * 8;
            const u16* gbp = wbt + (long)(n0 + (q >> 2)) * KIN + k0 + (q & 3) * 8;
            ld16(&As[q * 8], gap);
            ld16(&Bs[q * 8], gbp);
        }
        __syncthreads();
        short8 af[4], bfr[4];
        #pragma unroll
        for (int mi = 0; mi < 4; mi++)
            af[mi] = *(const short8*)&As[(wr + mi * 16 + lr) * 32 + lk * 8];
        #pragma unroll
        for (int nj = 0; nj < 4; nj++)
            bfr[nj] = *(const short8*)&Bs[(wc + nj * 16 + lr) * 32 + lk * 8];
        #pragma unroll
        for (int mi = 0; mi < 4; mi++)
            #pragma unroll
            for (int nj = 0; nj < 4; nj++)
                acc[mi][nj] = __builtin_amdgcn_mfma_f32_16x16x32_bf16(
                    af[mi], bfr[nj], acc[mi][nj], 0, 0, 0);
        __syncthreads();
    }
    // C/D map: col = wc + nj*16 + (lane&15), row = wr + mi*16 + (lane>>4)*4 + r
    #pragma unroll
    for (int mi = 0; mi < 4; mi++)
        #pragma unroll
        for (int r = 0; r < 4; r++) {
            int row = m0 + wr + mi * 16 + lk * 4 + r;
            u16* tp = t + (long)row * 512 + n0 + wc + lr;
            #pragma unroll
            for (int nj = 0; nj < 4; nj++)
                tp[nj * 16] = f2bf(acc[mi][nj][r]);
        }
    // ---- fused s1/s2: head h = n0>>7; s1[row,h] = sum_d t[row, h*128+d]*a[h,d] ----
    const int h = n0 >> 7;
    float a1c[4], a2c[4];
    #pragma unroll
    for (int nj = 0; nj < 4; nj++) {
        int col = wc + nj * 16 + lr;
        a1c[nj] = ag[h * 256 + col];
        a2c[nj] = ag[h * 256 + 128 + col];
    }
    float p1[16], p2[16];
    #pragma unroll
    for (int mi = 0; mi < 4; mi++)
        #pragma unroll
        for (int r = 0; r < 4; r++) {
            float v1 = 0.f, v2 = 0.f;
            #pragma unroll
            for (int nj = 0; nj < 4; nj++) {
                float tv = acc[mi][nj][r];
                v1 += tv * a1c[nj];
                v2 += tv * a2c[nj];
            }
            p1[mi * 4 + r] = v1;
            p2[mi * 4 + r] = v2;
        }
    #pragma unroll
    for (int off = 1; off < 16; off <<= 1)
        #pragma unroll
        for (int i = 0; i < 16; i++) {
            p1[i] += __shfl_xor(p1[i], off, 64);
            p2[i] += __shfl_xor(p2[i], off, 64);
        }
    if (lr == 0)
        #pragma unroll
        for (int mi = 0; mi < 4; mi++)
            #pragma unroll
            for (int r = 0; r < 4; r++) {
                int row = wr + mi * 16 + lk * 4 + r;
                sred[0][w & 1][row] = p1[mi * 4 + r];
                sred[1][w & 1][row] = p2[mi * 4 + r];
            }
    __syncthreads();
    if (tid < 128) {
        int row = m0 + tid;
        if (row < MROWS) {
            s1g[(long)row * 4 + h] = sred[0][0][tid] + sred[0][1][tid];
            s2g[(long)row * 4 + h] = sred[1][0][tid] + sred[1][1][tid];
        }
    }
}

// ---- kernel 2b: per-(b,h) node-wise maxes of s1,s2 -> block partials ----
__global__ void nodemax_kernel(const float* __restrict__ s1, const float* __restrict__ s2,
                               float* __restrict__ pmax) {
    int b = blockIdx.y, tid = threadIdx.x;
    float m1[4] = {-1e30f, -1e30f, -1e30f, -1e30f};
    float m2[4] = {-1e30f, -1e30f, -1e30f, -1e30f};
    for (int n = blockIdx.x * 256 + tid; n < Nn; n += 32 * 256) {
        float4 v1 = *(const float4*)(s1 + ((long)b * Nn + n) * 4);
        float4 v2 = *(const float4*)(s2 + ((long)b * Nn + n) * 4);
        m1[0] = fmaxf(m1[0], v1.x); m1[1] = fmaxf(m1[1], v1.y);
        m1[2] = fmaxf(m1[2], v1.z); m1[3] = fmaxf(m1[3], v1.w);
        m2[0] = fmaxf(m2[0], v2.x); m2[1] = fmaxf(m2[1], v2.y);
        m2[2] = fmaxf(m2[2], v2.z); m2[3] = fmaxf(m2[3], v2.w);
    }
    #pragma unroll
    for (int off = 1; off < 64; off <<= 1)
        #pragma unroll
        for (int h = 0; h < 4; h++) {
            m1[h] = fmaxf(m1[h], __shfl_xor(m1[h], off, 64));
            m2[h] = fmaxf(m2[h], __shfl_xor(m2[h], off, 64));
        }
    __shared__ float red[4][8];
    if ((tid & 63) == 0)
        #pragma unroll
        for (int h = 0; h < 4; h++) {
            red[tid >> 6][h] = m1[h];
            red[tid >> 6][h + 4] = m2[h];
        }
    __syncthreads();
    if (tid < 8) {
        float m = fmaxf(fmaxf(red[0][tid], red[1][tid]), fmaxf(red[2][tid], red[3][tid]));
        pmax[((b * 32 + blockIdx.x) * 8) + tid] = m;
    }
}

// ---- kernel 2c: reduce partials -> M[b*4+h] = leaky(m1+m2) (upper bound) ----
__global__ void mreduce_kernel(const float* __restrict__ pmax, float* __restrict__ M) {
    int tid = threadIdx.x;
    if (tid < 8) {
        int b = tid >> 2, h = tid & 3;
        float m1 = -1e30f, m2 = -1e30f;
        for (int blk = 0; blk < 32; blk++) {
            m1 = fmaxf(m1, pmax[(b * 32 + blk) * 8 + h]);
            m2 = fmaxf(m2, pmax[(b * 32 + blk) * 8 + 4 + h]);
        }
        float s = m1 + m2;
        M[tid] = s > 0.f ? s : 0.2f * s;
    }
}

// ---- kernel 3: fused edge pass: score + leaky + exp(.-M) + Z block partials ----
__global__ void edge_kernel(const int* __restrict__ ei, const float* __restrict__ s1,
                            const float* __restrict__ s2, const float* __restrict__ M,
                            float* __restrict__ p, float* __restrict__ Zpart) {
    int e = blockIdx.x * 256 + threadIdx.x;
    int b = blockIdx.y;
    float v[4] = {0.f, 0.f, 0.f, 0.f};
    float m0 = M[b * 4 + 0], m1 = M[b * 4 + 1], m2 = M[b * 4 + 2], m3 = M[b * 4 + 3];
    if (e < En) {
        int src = ei[e], dst = ei[En + e];
        float4 v1 = *(const float4*)(s1 + ((long)b * Nn + src) * 4);
        float4 v2 = *(const float4*)(s2 + ((long)b * Nn + dst) * 4);
        float s;
        s = v1.x + v2.x; s = s > 0.f ? s : 0.2f * s; v[0] = __expf(s - m0);
        s = v1.y + v2.y; s = s > 0.f ? s : 0.2f * s; v[1] = __expf(s - m1);
        s = v1.z + v2.z; s = s > 0.f ? s : 0.2f * s; v[2] = __expf(s - m2);
        s = v1.w + v2.w; s = s > 0.f ? s : 0.2f * s; v[3] = __expf(s - m3);
        float4 o = make_float4(v[0], v[1], v[2], v[3]);
        *(float4*)(p + ((long)b * En + e) * 4) = o;
    }
    #pragma unroll
    for (int off = 1; off < 64; off <<= 1)
        #pragma unroll
        for (int h = 0; h < 4; h++)
            v[h] += __shfl_xor(v[h], off, 64);
    __shared__ float red[4][4];
    int tid = threadIdx.x;
    if ((tid & 63) == 0)
        #pragma unroll
        for (int h = 0; h < 4; h++)
            red[tid >> 6][h] = v[h];
    __syncthreads();
    if (tid < 4) {
        float z = red[0][tid] + red[1][tid] + red[2][tid] + red[3][tid];
        Zpart[((long)b * EBLK + blockIdx.x) * 4 + tid] = z;
    }
}

// ---- kernel 4: reduce Z partials -> invZ[b*4+h] ----
__global__ void zreduce_kernel(const float* __restrict__ Zpart, float* __restrict__ invZ) {
    int tid = threadIdx.x;
    int g = tid >> 6, l = tid & 63;
    int b = g >> 2, h = g & 3;
    float s = 0.f;
    for (int i = l; i < EBLK; i += 64)
        s += Zpart[((long)b * EBLK + i) * 4 + h];
    #pragma unroll
    for (int off = 1; off < 64; off <<= 1)
        s += __shfl_xor(s, off, 64);
    if (l == 0) invZ[g] = 1.0f / s;
}

// ---- kernel 5a: degree histogram ----
__global__ void hist_kernel(const int* __restrict__ ei, int* __restrict__ deg) {
    int e = blockIdx.x * 256 + threadIdx.x;
    if (e < En) atomicAdd(&deg[ei[En + e]], 1);
}

// ---- kernel 5b: exclusive scan (single block, 1024 threads) ----
__global__ void scan_kernel(const int* __restrict__ deg, int* __restrict__ offs,
                            int* __restrict__ cursor) {
    __shared__ int part[1024];
    int tid = threadIdx.x;
    const int CH = (Nn + 1023) / 1024;  // 30
    int start = tid * CH;
    int s = 0;
    for (int i = 0; i < CH; i++) {
        int n = start + i;
        if (n < Nn) s += deg[n];
    }
    part[tid] = s;
    __syncthreads();
    for (int off = 1; off < 1024; off <<= 1) {
        int x = (tid >= off) ? part[tid - off] : 0;
        __syncthreads();
        part[tid] += x;
        __syncthreads();
    }
    int run = part[tid] - s;
    for (int i = 0; i < CH; i++) {
        int n = start + i;
        if (n < Nn) {
            offs[n] = run;
            cursor[n] = run;
            run += deg[n];
        }
    }
    if (tid == 1023) offs[Nn] = part[1023];
}

// ---- kernel 5c: scatter: dst-sorted srcs + dst-sorted softmax numerators ----
__global__ void scatter_kernel(const int* __restrict__ ei, const float* __restrict__ p,
                               int* __restrict__ cursor, int* __restrict__ srcs,
                               float* __restrict__ pw) {
    int e = blockIdx.x * 256 + threadIdx.x;
    if (e >= En) return;
    int src = ei[e], dst = ei[En + e];
    int pos = atomicAdd(&cursor[dst], 1);
    srcs[pos] = src;
    *(float4*)(pw + (long)pos * 4)        = *(const float4*)(p + (long)e * 4);
    *(float4*)(pw + ((long)En + pos) * 4) = *(const float4*)(p + ((long)En + e) * 4);
}

// ---- kernel 6: aggregation (no atomics, 2-deep chain, x4 unrolled MLP) + fused LN ----
__launch_bounds__(256)
__global__ void agg_kernel(const u16* __restrict__ t, const int* __restrict__ srcs,
                           const float* __restrict__ pw, const float* __restrict__ invZ,
                           const int* __restrict__ offs,
                           const float* __restrict__ gamma, const float* __restrict__ beta,
                           float* __restrict__ out) {
    int tid = threadIdx.x;
    int lid = tid & 127;                 // owns cols 4*lid .. 4*lid+3
    int n = blockIdx.x * 2 + (tid >> 7); // 2 nodes per block
    int b = blockIdx.y;
    int h = lid >> 5;
    int j0 = offs[n], j1 = offs[n + 1];
    const float* pwb = pw + (long)b * En * 4;
    const u16* tb = t + (long)b * Nn * 512;
    float a0 = 0.f, a1 = 0.f, a2 = 0.f, a3 = 0.f;
    int j = j0;
    for (; j + 4 <= j1; j += 4) {
        int s0 = srcs[j], s1i = srcs[j + 1], s2i = srcs[j + 2], s3i = srcs[j + 3];
        float w0 = pwb[(long)j * 4 + h];
        float w1 = pwb[(long)(j + 1) * 4 + h];
        float w2 = pwb[(long)(j + 2) * 4 + h];
        float w3 = pwb[(long)(j + 3) * 4 + h];
        uint2 r0 = *(const uint2*)(tb + (long)s0 * 512 + lid * 4);
        uint2 r1 = *(const uint2*)(tb + (long)s1i * 512 + lid * 4);
        uint2 r2 = *(const uint2*)(tb + (long)s2i * 512 + lid * 4);
        uint2 r3 = *(const uint2*)(tb + (long)s3i * 512 + lid * 4);
        a0 += w0 * bflo(r0.x) + w1 * bflo(r1.x) + w2 * bflo(r2.x) + w3 * bflo(r3.x);
        a1 += w0 * bfhi(r0.x) + w1 * bfhi(r1.x) + w2 * bfhi(r2.x) + w3 * bfhi(r3.x);
        a2 += w0 * bflo(r0.y) + w1 * bflo(r1.y) + w2 * bflo(r2.y) + w3 * bflo(r3.y);
        a3 += w0 * bfhi(r0.y) + w1 * bfhi(r1.y) + w2 * bfhi(r2.y) + w3 * bfhi(r3.y);
    }
    for (; j < j1; j++) {
        int s0 = srcs[j];
        float w0 = pwb[(long)j * 4 + h];
        uint2 r0 = *(const uint2*)(tb + (long)s0 * 512 + lid * 4);
        a0 += w0 * bflo(r0.x);
        a1 += w0 * bfhi(r0.x);
        a2 += w0 * bflo(r0.y);
        a3 += w0 * bfhi(r0.y);
    }
    float invz = invZ[b * 4 + h];
    a0 *= invz; a1 *= invz; a2 *= invz; a3 *= invz;
    // fused LayerNorm over this node's 512 cols (128 threads = 2 waves)
    float s  = a0 + a1 + a2 + a3;
    float ss = a0 * a0 + a1 * a1 + a2 * a2 + a3 * a3;
    #pragma unroll
    for (int off = 1; off < 64; off <<= 1) {
        s  += __shfl_xor(s, off, 64);
        ss += __shfl_xor(ss, off, 64);
    }
    __shared__ float red[4][2];
    int wv = tid >> 6;
    if ((tid & 63) == 0) { red[wv][0] = s; red[wv][1] = ss; }
    __syncthreads();
    int base = (tid >> 7) * 2;
    s  = red[base][0] + red[base + 1][0];
    ss = red[base][1] + red[base + 1][1];
    float mean = s * (1.0f / 512.0f);
    float var = ss * (1.0f / 512.0f) - mean * mean;
    var = var < 0.f ? 0.f : var;
    float scale = rsqrtf(var + LNEPS);
    int c = lid * 4;
    float4 o;
    o.x = (a0 - mean) * scale * gamma[c + 0] + beta[c + 0];
    o.y = (a1 - mean) * scale * gamma[c + 1] + beta[c + 1];
    o.z = (a2 - mean) * scale * gamma[c + 2] + beta[c + 2];
    o.w = (a3 - mean) * scale * gamma[c + 3] + beta[c + 3];
    *(float4*)(out + ((long)b * Nn + n) * 512 + c) = o;
}

extern "C" void kernel_launch(void* const* d_in, const int* in_sizes, int n_in,
                              void* d_out, int out_size, void* d_ws, size_t ws_size,
                              hipStream_t stream) {
    const float* x     = (const float*)d_in[0];
    const int*   ei    = (const int*)d_in[1];   // (2,E) int32
    const float* W     = (const float*)d_in[2];
    const float* a     = (const float*)d_in[3];
    const float* gamma = (const float*)d_in[4];
    const float* beta  = (const float*)d_in[5];
    float* out = (float*)d_out;

    char* ws = (char*)d_ws;
    size_t off = 0;
    auto alloc = [&](size_t bytes) -> void* {
        void* ptr = ws + off;
        off = (off + bytes + 255) & ~(size_t)255;
        return ptr;
    };
    u16*   xb     = (u16*)alloc((size_t)MPAD * KIN * 2);       // 61.5 MB
    u16*   wbt    = (u16*)alloc((size_t)512 * 512 * 2);        // 0.5 MB
    u16*   t      = (u16*)alloc((size_t)MPAD * 512 * 2);       // 61.5 MB
    float* s1     = (float*)alloc((size_t)MROWS * 4 * 4);
    float* s2     = (float*)alloc((size_t)MROWS * 4 * 4);
    float* p      = (float*)alloc((size_t)Bn * En * 4 * 4);    // softmax numerators
    float* pw     = (float*)alloc((size_t)Bn * En * 4 * 4);    // dst-sorted numerators
    float* pmax   = (float*)alloc((size_t)Bn * 32 * 8 * 4);
    float* M      = (float*)alloc(8 * 4);
    float* Zpart  = (float*)alloc((size_t)Bn * EBLK * 4 * 4);
    float* invZ   = (float*)alloc(8 * 4);
    int*   deg    = (int*)alloc((size_t)Nn * 4);
    int*   offs   = (int*)alloc((size_t)(Nn + 1) * 4);
    int*   cursor = (int*)alloc((size_t)Nn * 4);
    int*   srcs   = (int*)alloc((size_t)En * 4);

    hipMemsetAsync(deg, 0, (size_t)Nn * 4, stream);

    cvt_x<<<(int)(((long)MPAD * KIN / 8 + 255) / 256), 256, 0, stream>>>(x, xb);
    cvt_w<<<(512 * 512) / 256, 256, 0, stream>>>(W, wbt);
    gemm<<<dim3(4, MPAD / 128), 256, 0, stream>>>(xb, wbt, a, t, s1, s2);
    nodemax_kernel<<<dim3(32, Bn), 256, 0, stream>>>(s1, s2, pmax);
    mreduce_kernel<<<1, 64, 0, stream>>>(pmax, M);
    edge_kernel<<<dim3(EBLK, Bn), 256, 0, stream>>>(ei, s1, s2, M, p, Zpart);
    zreduce_kernel<<<1, 512, 0, stream>>>(Zpart, invZ);
    hist_kernel<<<(En + 255) / 256, 256, 0, stream>>>(ei, deg);
    scan_kernel<<<1, 1024, 0, stream>>>(deg, offs, cursor);
    scatter_kernel<<<(En + 255) / 256, 256, 0, stream>>>(ei, p, cursor, srcs, pw);
    agg_kernel<<<dim3(Nn / 2, Bn), 256, 0, stream>>>(t, srcs, pw, invZ, offs, gamma, beta, out);
}

// Round 4
// 411.979 us; speedup vs baseline: 1.9197x; 1.0424x over previous
//
#include <hip/hip_runtime.h>
#include <stdint.h>

#define Bn 2
#define Nn 30000
#define En 120000
#define KIN 512
#define Hh 4
#define Dd 128
#define MROWS 60000            // B*N rows
#define MPAD  60032            // 469 * 128
#define LNEPS 1e-5f
#define EBLK 469               // ceil(En/256)

typedef unsigned short u16;
typedef unsigned int   u32;
typedef __attribute__((ext_vector_type(8))) short short8;
typedef __attribute__((ext_vector_type(4))) float f32x4;

__device__ __forceinline__ u16 f2bf(float f) {
    u32 u = __builtin_bit_cast(u32, f);
    u32 r = u + 0x7FFFu + ((u >> 16) & 1u);
    return (u16)(r >> 16);
}
__device__ __forceinline__ float bflo(u32 u) {
    return __builtin_bit_cast(float, u << 16);
}
__device__ __forceinline__ float bfhi(u32 u) {
    return __builtin_bit_cast(float, u & 0xFFFF0000u);
}
__device__ __forceinline__ void ld16(void* lds, const void* g) {
    __builtin_amdgcn_global_load_lds((const __attribute__((address_space(1))) void*)g,
                                     (__attribute__((address_space(3))) void*)lds, 16, 0, 0);
}

// ---- kernel 1: prep = cvt_x (15008 blocks) + cvt_w (1024) + hist (469) ----
#define CVTX_BLKS 15008        // MPAD*KIN/8/256 exactly
#define CVTW_BLKS 1024         // 512*512/256 exactly
__global__ void prep_kernel(const float* __restrict__ x, u16* __restrict__ xb,
                            const float* __restrict__ W, u16* __restrict__ wbt,
                            const int* __restrict__ ei, int* __restrict__ deg) {
    int blk = blockIdx.x;
    if (blk < CVTX_BLKS) {
        long base = ((long)blk * 256 + threadIdx.x) * 8;
        short8 o = {};
        if (base < (long)MROWS * KIN) {
            const float4* px = (const float4*)(x + base);
            float4 v0 = px[0], v1 = px[1];
            o[0] = (short)f2bf(v0.x); o[1] = (short)f2bf(v0.y);
            o[2] = (short)f2bf(v0.z); o[3] = (short)f2bf(v0.w);
            o[4] = (short)f2bf(v1.x); o[5] = (short)f2bf(v1.y);
            o[6] = (short)f2bf(v1.z); o[7] = (short)f2bf(v1.w);
        }
        *(short8*)(xb + base) = o;
    } else if (blk < CVTX_BLKS + CVTW_BLKS) {
        int idx = (blk - CVTX_BLKS) * 256 + threadIdx.x;
        int c = idx >> 9, i = idx & 511;
        int h = c >> 7, d = c & 127;
        wbt[idx] = f2bf(W[h * (KIN * Dd) + i * Dd + d]);
    } else {
        int e = (blk - CVTX_BLKS - CVTW_BLKS) * 256 + threadIdx.x;
        if (e < En) atomicAdd(&deg[ei[En + e]], 1);
    }
}

// ---- scan as a device function: 256 threads, exclusive scan of deg[30000] ----
__device__ void scan256(const int* __restrict__ deg, int* __restrict__ offs,
                        int* __restrict__ cursor) {
    __shared__ int part[256];
    int tid = threadIdx.x;
    const int CH = 118;                // 256*118 = 30208 >= Nn
    int start = tid * CH;
    int s = 0;
    for (int i = 0; i < CH; i++) {
        int n = start + i;
        if (n < Nn) s += deg[n];
    }
    part[tid] = s;
    __syncthreads();
    for (int off = 1; off < 256; off <<= 1) {
        int xv = (tid >= off) ? part[tid - off] : 0;
        __syncthreads();
        part[tid] += xv;
        __syncthreads();
    }
    int run = part[tid] - s;
    for (int i = 0; i < CH; i++) {
        int n = start + i;
        if (n < Nn) {
            offs[n] = run;
            cursor[n] = run;
            run += deg[n];
        }
    }
    if (tid == 255) offs[Nn] = part[255];
}

// ---- kernel 2: GEMM t = xb * wbt^T (bf16 MFMA, m97 pattern) + fused s1/s2 epilogue
//      blockIdx.y == 469 hosts the prefix scan (hides under gemm). ----
__launch_bounds__(256)
__global__ void gemm(const u16* __restrict__ xb, const u16* __restrict__ wbt,
                     const float* __restrict__ ag, u16* __restrict__ t,
                     float* __restrict__ s1g, float* __restrict__ s2g,
                     const int* __restrict__ deg, int* __restrict__ offs,
                     int* __restrict__ cursor) {
    if (blockIdx.y == 469) {
        if (blockIdx.x == 0) scan256(deg, offs, cursor);
        return;
    }
    __shared__ __align__(16) u16 As[128 * 32];
    __shared__ __align__(16) u16 Bs[128 * 32];
    __shared__ float sred[2][2][128];   // [s1/s2][col-half][row]
    const int tid = threadIdx.x;
    const int m0 = blockIdx.y * 128, n0 = blockIdx.x * 128;
    const int w = tid >> 6, l = tid & 63;
    const int wr = (w >> 1) * 64, wc = (w & 1) * 64;
    const int lr = l & 15, lk = l >> 4;
    f32x4 acc[4][4] = {};

    for (int k0 = 0; k0 < KIN; k0 += 32) {
        #pragma unroll
        for (int inst = 0; inst < 2; inst++) {
            int q = inst * 256 + tid;
            const u16* gap = xb  + (long)(m0 + (q >> 2)) * KIN + k0 + (q & 3) * 8;
            const u16* gbp = wbt + (long)(n0 + (q >> 2)) * KIN + k0 + (q & 3) * 8;
            ld16(&As[q * 8], gap);
            ld16(&Bs[q * 8], gbp);
        }
        __syncthreads();
        short8 af[4], bfr[4];
        #pragma unroll
        for (int mi = 0; mi < 4; mi++)
            af[mi] = *(const short8*)&As[(wr + mi * 16 + lr) * 32 + lk * 8];
        #pragma unroll
        for (int nj = 0; nj < 4; nj++)
            bfr[nj] = *(const short8*)&Bs[(wc + nj * 16 + lr) * 32 + lk * 8];
        #pragma unroll
        for (int mi = 0; mi < 4; mi++)
            #pragma unroll
            for (int nj = 0; nj < 4; nj++)
                acc[mi][nj] = __builtin_amdgcn_mfma_f32_16x16x32_bf16(
                    af[mi], bfr[nj], acc[mi][nj], 0, 0, 0);
        __syncthreads();
    }
    // C/D map: col = wc + nj*16 + (lane&15), row = wr + mi*16 + (lane>>4)*4 + r
    #pragma unroll
    for (int mi = 0; mi < 4; mi++)
        #pragma unroll
        for (int r = 0; r < 4; r++) {
            int row = m0 + wr + mi * 16 + lk * 4 + r;
            u16* tp = t + (long)row * 512 + n0 + wc + lr;
            #pragma unroll
            for (int nj = 0; nj < 4; nj++)
                tp[nj * 16] = f2bf(acc[mi][nj][r]);
        }
    // ---- fused s1/s2 (head h = n0>>7) from fp32 accumulators ----
    const int h = n0 >> 7;
    float a1c[4], a2c[4];
    #pragma unroll
    for (int nj = 0; nj < 4; nj++) {
        int col = wc + nj * 16 + lr;
        a1c[nj] = ag[h * 256 + col];
        a2c[nj] = ag[h * 256 + 128 + col];
    }
    float p1[16], p2[16];
    #pragma unroll
    for (int mi = 0; mi < 4; mi++)
        #pragma unroll
        for (int r = 0; r < 4; r++) {
            float v1 = 0.f, v2 = 0.f;
            #pragma unroll
            for (int nj = 0; nj < 4; nj++) {
                float tv = acc[mi][nj][r];
                v1 += tv * a1c[nj];
                v2 += tv * a2c[nj];
            }
            p1[mi * 4 + r] = v1;
            p2[mi * 4 + r] = v2;
        }
    #pragma unroll
    for (int off = 1; off < 16; off <<= 1)
        #pragma unroll
        for (int i = 0; i < 16; i++) {
            p1[i] += __shfl_xor(p1[i], off, 64);
            p2[i] += __shfl_xor(p2[i], off, 64);
        }
    if (lr == 0)
        #pragma unroll
        for (int mi = 0; mi < 4; mi++)
            #pragma unroll
            for (int r = 0; r < 4; r++) {
                int row = wr + mi * 16 + lk * 4 + r;
                sred[0][w & 1][row] = p1[mi * 4 + r];
                sred[1][w & 1][row] = p2[mi * 4 + r];
            }
    __syncthreads();
    if (tid < 128) {
        int row = m0 + tid;
        if (row < MROWS) {
            s1g[(long)row * 4 + h] = sred[0][0][tid] + sred[0][1][tid];
            s2g[(long)row * 4 + h] = sred[1][0][tid] + sred[1][1][tid];
        }
    }
}

// ---- kernel 3: fused edge pass: score + leaky + exp (no shift; scores |s|<~10)
//      + dst-sorted scatter of srcs/pw + Z block partials, both batches ----
__global__ void edgescatter_kernel(const int* __restrict__ ei, const float* __restrict__ s1,
                                   const float* __restrict__ s2, int* __restrict__ cursor,
                                   int* __restrict__ srcs, float* __restrict__ pw,
                                   float* __restrict__ Zpart) {
    int e = blockIdx.x * 256 + threadIdx.x;
    int tid = threadIdx.x;
    float v[8] = {0.f, 0.f, 0.f, 0.f, 0.f, 0.f, 0.f, 0.f};
    if (e < En) {
        int src = ei[e], dst = ei[En + e];
        #pragma unroll
        for (int b = 0; b < Bn; b++) {
            float4 v1 = *(const float4*)(s1 + ((long)b * Nn + src) * 4);
            float4 v2 = *(const float4*)(s2 + ((long)b * Nn + dst) * 4);
            float s;
            s = v1.x + v2.x; s = s > 0.f ? s : 0.2f * s; v[b * 4 + 0] = __expf(s);
            s = v1.y + v2.y; s = s > 0.f ? s : 0.2f * s; v[b * 4 + 1] = __expf(s);
            s = v1.z + v2.z; s = s > 0.f ? s : 0.2f * s; v[b * 4 + 2] = __expf(s);
            s = v1.w + v2.w; s = s > 0.f ? s : 0.2f * s; v[b * 4 + 3] = __expf(s);
        }
        int pos = atomicAdd(&cursor[dst], 1);
        srcs[pos] = src;
        *(float4*)(pw + (long)pos * 4)        = make_float4(v[0], v[1], v[2], v[3]);
        *(float4*)(pw + ((long)En + pos) * 4) = make_float4(v[4], v[5], v[6], v[7]);
    }
    #pragma unroll
    for (int off = 1; off < 64; off <<= 1)
        #pragma unroll
        for (int i = 0; i < 8; i++)
            v[i] += __shfl_xor(v[i], off, 64);
    __shared__ float red[4][8];
    if ((tid & 63) == 0)
        #pragma unroll
        for (int i = 0; i < 8; i++)
            red[tid >> 6][i] = v[i];
    __syncthreads();
    if (tid < 8)
        Zpart[(long)blockIdx.x * 8 + tid] =
            red[0][tid] + red[1][tid] + red[2][tid] + red[3][tid];
}

// ---- kernel 4: reduce Z partials -> invZ[b*4+h] (256 thr = 8 groups x 32 lanes) ----
__global__ void zreduce_kernel(const float* __restrict__ Zpart, float* __restrict__ invZ) {
    int tid = threadIdx.x;
    int g = tid >> 5, l = tid & 31;
    float s = 0.f;
    for (int i = l; i < EBLK; i += 32)
        s += Zpart[(long)i * 8 + g];
    #pragma unroll
    for (int off = 1; off < 32; off <<= 1)
        s += __shfl_xor(s, off, 64);   // off<32 stays within the 32-lane half
    if (l == 0) invZ[g] = 1.0f / s;
}

// ---- kernel 5: aggregation (no atomics, 2-deep chain, x4 unrolled MLP) + fused LN ----
__launch_bounds__(128)
__global__ void agg_kernel(const u16* __restrict__ t, const int* __restrict__ srcs,
                           const float* __restrict__ pw, const float* __restrict__ invZ,
                           const int* __restrict__ offs,
                           const float* __restrict__ gamma, const float* __restrict__ beta,
                           float* __restrict__ out) {
    int tid = threadIdx.x;               // owns cols 4*tid .. 4*tid+3
    int n = blockIdx.x;
    int b = blockIdx.y;
    int h = tid >> 5;
    int j0 = offs[n], j1 = offs[n + 1];
    const float* pwb = pw + (long)b * En * 4;
    const u16* tb = t + (long)b * Nn * 512;
    float a0 = 0.f, a1 = 0.f, a2 = 0.f, a3 = 0.f;
    int j = j0;
    for (; j + 4 <= j1; j += 4) {
        int s0 = srcs[j], s1i = srcs[j + 1], s2i = srcs[j + 2], s3i = srcs[j + 3];
        float w0 = pwb[(long)j * 4 + h];
        float w1 = pwb[(long)(j + 1) * 4 + h];
        float w2 = pwb[(long)(j + 2) * 4 + h];
        float w3 = pwb[(long)(j + 3) * 4 + h];
        uint2 r0 = *(const uint2*)(tb + (long)s0 * 512 + tid * 4);
        uint2 r1 = *(const uint2*)(tb + (long)s1i * 512 + tid * 4);
        uint2 r2 = *(const uint2*)(tb + (long)s2i * 512 + tid * 4);
        uint2 r3 = *(const uint2*)(tb + (long)s3i * 512 + tid * 4);
        a0 += w0 * bflo(r0.x) + w1 * bflo(r1.x) + w2 * bflo(r2.x) + w3 * bflo(r3.x);
        a1 += w0 * bfhi(r0.x) + w1 * bfhi(r1.x) + w2 * bfhi(r2.x) + w3 * bfhi(r3.x);
        a2 += w0 * bflo(r0.y) + w1 * bflo(r1.y) + w2 * bflo(r2.y) + w3 * bflo(r3.y);
        a3 += w0 * bfhi(r0.y) + w1 * bfhi(r1.y) + w2 * bfhi(r2.y) + w3 * bfhi(r3.y);
    }
    for (; j < j1; j++) {
        int s0 = srcs[j];
        float w0 = pwb[(long)j * 4 + h];
        uint2 r0 = *(const uint2*)(tb + (long)s0 * 512 + tid * 4);
        a0 += w0 * bflo(r0.x);
        a1 += w0 * bfhi(r0.x);
        a2 += w0 * bflo(r0.y);
        a3 += w0 * bfhi(r0.y);
    }
    float invz = invZ[b * 4 + h];
    a0 *= invz; a1 *= invz; a2 *= invz; a3 *= invz;
    // fused LayerNorm over this node's 512 cols (128 threads = 2 waves)
    float s  = a0 + a1 + a2 + a3;
    float ss = a0 * a0 + a1 * a1 + a2 * a2 + a3 * a3;
    #pragma unroll
    for (int off = 1; off < 64; off <<= 1) {
        s  += __shfl_xor(s, off, 64);
        ss += __shfl_xor(ss, off, 64);
    }
    __shared__ float red[2][2];
    int wv = tid >> 6;
    if ((tid & 63) == 0) { red[wv][0] = s; red[wv][1] = ss; }
    __syncthreads();
    s  = red[0][0] + red[1][0];
    ss = red[0][1] + red[1][1];
    float mean = s * (1.0f / 512.0f);
    float var = ss * (1.0f / 512.0f) - mean * mean;
    var = var < 0.f ? 0.f : var;
    float scale = rsqrtf(var + LNEPS);
    int c = tid * 4;
    float4 o;
    o.x = (a0 - mean) * scale * gamma[c + 0] + beta[c + 0];
    o.y = (a1 - mean) * scale * gamma[c + 1] + beta[c + 1];
    o.z = (a2 - mean) * scale * gamma[c + 2] + beta[c + 2];
    o.w = (a3 - mean) * scale * gamma[c + 3] + beta[c + 3];
    *(float4*)(out + ((long)b * Nn + n) * 512 + c) = o;
}

extern "C" void kernel_launch(void* const* d_in, const int* in_sizes, int n_in,
                              void* d_out, int out_size, void* d_ws, size_t ws_size,
                              hipStream_t stream) {
    const float* x     = (const float*)d_in[0];
    const int*   ei    = (const int*)d_in[1];   // (2,E) int32
    const float* W     = (const float*)d_in[2];
    const float* a     = (const float*)d_in[3];
    const float* gamma = (const float*)d_in[4];
    const float* beta  = (const float*)d_in[5];
    float* out = (float*)d_out;

    char* ws = (char*)d_ws;
    size_t off = 0;
    auto alloc = [&](size_t bytes) -> void* {
        void* ptr = ws + off;
        off = (off + bytes + 255) & ~(size_t)255;
        return ptr;
    };
    u16*   xb     = (u16*)alloc((size_t)MPAD * KIN * 2);       // 61.5 MB
    u16*   wbt    = (u16*)alloc((size_t)512 * 512 * 2);        // 0.5 MB
    u16*   t      = (u16*)alloc((size_t)MPAD * 512 * 2);       // 61.5 MB
    float* s1     = (float*)alloc((size_t)MROWS * 4 * 4);
    float* s2     = (float*)alloc((size_t)MROWS * 4 * 4);
    float* pw     = (float*)alloc((size_t)Bn * En * 4 * 4);    // dst-sorted numerators
    float* Zpart  = (float*)alloc((size_t)EBLK * 8 * 4);
    float* invZ   = (float*)alloc(8 * 4);
    int*   deg    = (int*)alloc((size_t)Nn * 4);
    int*   offs   = (int*)alloc((size_t)(Nn + 1) * 4);
    int*   cursor = (int*)alloc((size_t)Nn * 4);
    int*   srcs   = (int*)alloc((size_t)En * 4);

    hipMemsetAsync(deg, 0, (size_t)Nn * 4, stream);

    prep_kernel<<<CVTX_BLKS + CVTW_BLKS + EBLK, 256, 0, stream>>>(x, xb, W, wbt, ei, deg);
    gemm<<<dim3(4, 470), 256, 0, stream>>>(xb, wbt, a, t, s1, s2, deg, offs, cursor);
    edgescatter_kernel<<<EBLK, 256, 0, stream>>>(ei, s1, s2, cursor, srcs, pw, Zpart);
    zreduce_kernel<<<1, 256, 0, stream>>>(Zpart, invZ);
    agg_kernel<<<dim3(Nn, Bn), 128, 0, stream>>>(t, srcs, pw, invZ, offs, gamma, beta, out);
}